// Round 1
// baseline (2061.470 us; speedup 1.0000x reference)
//
#include <hip/hip_runtime.h>
#include <math.h>

#define T_TOK 32768      // B*N = 2*16384
#define DIM 128
#define NHEADS 4
#define HD 32
#define NEXP 16
#define EHID 256
#define NWIN 512         // B * 16 * 16
#define EPS 1e-5f

// ---------------- LN1 (wave per token) + zero counts ----------------
__global__ __launch_bounds__(256) void k_ln1(const float* __restrict__ x,
                                             const float* __restrict__ g,
                                             const float* __restrict__ b,
                                             float* __restrict__ y,
                                             int* __restrict__ counts) {
    int tid = threadIdx.x, wv = tid >> 6, lane = tid & 63;
    if (blockIdx.x == 0 && tid < NEXP) counts[tid] = 0;
    size_t t = (size_t)blockIdx.x * 4 + wv;
    const float* xr = x + t * DIM;
    float2 v = *(const float2*)(xr + lane * 2);
    float s = v.x + v.y, sq = v.x * v.x + v.y * v.y;
    #pragma unroll
    for (int o = 32; o; o >>= 1) { s += __shfl_xor(s, o); sq += __shfl_xor(sq, o); }
    float m = s * (1.f / DIM);
    float var = sq * (1.f / DIM) - m * m;
    float rs = rsqrtf(var + EPS);
    int k = lane * 2;
    float y0 = (v.x - m) * rs * g[k] + b[k];
    float y1 = (v.y - m) * rs * g[k + 1] + b[k + 1];
    *(float2*)(y + t * DIM + k) = make_float2(y0, y1);
}

// ---------------- fused windowed attention (block per 8x8 window) ----------------
__global__ __launch_bounds__(256) void k_attn(const float* __restrict__ x,
                                              const float* __restrict__ y,
                                              const float* __restrict__ w_qkv,
                                              const float* __restrict__ b_qkv,
                                              const float* __restrict__ w_proj,
                                              const float* __restrict__ b_proj,
                                              float* __restrict__ x2) {
    __shared__ float xw[64][129];    // window rows of y1; later reused as attn output ow
    __shared__ float qkv[64][387];   // [token][0:128]=q [128:256]=k [256:384]=v (pad->387)
    __shared__ float sc[64][65];     // per-head score/attn matrix

    int tid = threadIdx.x, wv = tid >> 6, lane = tid & 63;
    int wid = blockIdx.x;
    int wb = wid >> 8;               // batch
    int wrr = (wid >> 4) & 15, wcc = wid & 15;
    // float offset of token (row wrr*8, col wcc*8) of batch wb
    const size_t base = ((size_t)wb * 16384 + (size_t)wrr * 1024 + (size_t)wcc * 8) * DIM;
    // token tt=(r,cc): float offset = base + r*16384 + cc*128

    // stage window rows (coalesced 4KB runs per window row)
    for (int i = tid; i < 64 * DIM; i += 256) {
        int tt = i >> 7, k = i & 127;
        xw[tt][k] = y[base + (size_t)(tt >> 3) * 16384 + (size_t)(tt & 7) * DIM + k];
    }
    __syncthreads();

    // QKV: wave wv handles outputs o = wv, wv+4, ...; lane = token
    for (int o = wv; o < 3 * DIM; o += 4) {
        const float* wrow = w_qkv + o * DIM;
        float acc = b_qkv[o];
        #pragma unroll 4
        for (int k = 0; k < DIM; ++k) acc = fmaf(xw[lane][k], wrow[k], acc);
        qkv[lane][o] = acc;
    }
    __syncthreads();

    for (int h = 0; h < NHEADS; ++h) {
        int qo = h * HD, ko = DIM + qo, vo = 2 * DIM + qo;
        // scores: wave wv -> rows wv*16..wv*16+15, lane = column
        for (int ii = 0; ii < 16; ++ii) {
            int i = wv * 16 + ii;
            float acc = 0.f;
            #pragma unroll
            for (int d = 0; d < HD; ++d) acc = fmaf(qkv[i][qo + d], qkv[lane][ko + d], acc);
            sc[i][lane] = acc * 0.17677669529663687f;  // 1/sqrt(32)
        }
        __syncthreads();
        // softmax per row (64 lanes = 64 cols)
        for (int ii = 0; ii < 16; ++ii) {
            int i = wv * 16 + ii;
            float v0 = sc[i][lane];
            float mx = v0;
            #pragma unroll
            for (int o = 32; o; o >>= 1) mx = fmaxf(mx, __shfl_xor(mx, o));
            float e0 = expf(v0 - mx);
            float ssum = e0;
            #pragma unroll
            for (int o = 32; o; o >>= 1) ssum += __shfl_xor(ssum, o);
            sc[i][lane] = e0 / ssum;
        }
        __syncthreads();
        // AV: lane = (d, half); write into xw (reused as output)
        int d = lane & 31, ih = lane >> 5;
        for (int ii = 0; ii < 8; ++ii) {
            int i = (wv << 1) + ih + (ii << 3);
            float acc = 0.f;
            #pragma unroll 4
            for (int j = 0; j < 64; ++j) acc = fmaf(sc[i][j], qkv[j][vo + d], acc);
            xw[i][qo + d] = acc;
        }
        __syncthreads();
    }

    // proj + residual -> x2
    int c = tid & 127, th = tid >> 7;
    const float* wp = w_proj + c * DIM;
    float bp = b_proj[c];
    for (int t2 = 0; t2 < 32; ++t2) {
        int tt = th + (t2 << 1);
        float acc = bp;
        #pragma unroll 4
        for (int k = 0; k < DIM; ++k) acc = fmaf(xw[tt][k], wp[k], acc);
        size_t go = base + (size_t)(tt >> 3) * 16384 + (size_t)(tt & 7) * DIM + c;
        x2[go] = x[go] + acc;
    }
}

// ---------------- LN2 + gate + top-1 routing ----------------
__global__ __launch_bounds__(256) void k_ln2_gate(const float* __restrict__ x2,
                                                  const float* __restrict__ g,
                                                  const float* __restrict__ b,
                                                  const float* __restrict__ gw,
                                                  float* __restrict__ y,
                                                  int* __restrict__ eidx,
                                                  float* __restrict__ wgt,
                                                  int* __restrict__ counts) {
    int tid = threadIdx.x, wv = tid >> 6, lane = tid & 63;
    size_t t = (size_t)blockIdx.x * 4 + wv;
    const float* xr = x2 + t * DIM;
    float2 v = *(const float2*)(xr + lane * 2);
    float s = v.x + v.y, sq = v.x * v.x + v.y * v.y;
    #pragma unroll
    for (int o = 32; o; o >>= 1) { s += __shfl_xor(s, o); sq += __shfl_xor(sq, o); }
    float m = s * (1.f / DIM);
    float var = sq * (1.f / DIM) - m * m;
    float rs = rsqrtf(var + EPS);
    int k = lane * 2;
    float y0 = (v.x - m) * rs * g[k] + b[k];
    float y1 = (v.y - m) * rs * g[k + 1] + b[k + 1];
    *(float2*)(y + t * DIM + k) = make_float2(y0, y1);

    float lg[NEXP];
    #pragma unroll
    for (int e = 0; e < NEXP; ++e) {
        float p = y0 * gw[e * DIM + k] + y1 * gw[e * DIM + k + 1];
        #pragma unroll
        for (int o = 32; o; o >>= 1) p += __shfl_xor(p, o);
        lg[e] = p;
    }
    float mx = lg[0]; int am = 0;
    #pragma unroll
    for (int e = 1; e < NEXP; ++e) if (lg[e] > mx) { mx = lg[e]; am = e; }
    float ssum = 0.f;
    #pragma unroll
    for (int e = 0; e < NEXP; ++e) ssum += expf(lg[e] - mx);
    float p = 1.f / ssum;            // top-1 softmax prob
    float w = p / (p + 1e-8f);
    if (lane == 0) {
        eidx[t] = am;
        wgt[t] = w;
        atomicAdd(&counts[am], 1);
    }
}

// ---------------- bucket scan + scatter ----------------
__global__ void k_scan(const int* __restrict__ counts, int* __restrict__ offsets,
                       int* __restrict__ fill) {
    if (threadIdx.x == 0) {
        int off = 0;
        for (int e = 0; e < NEXP; ++e) { offsets[e] = off; fill[e] = off; off += counts[e]; }
    }
}

__global__ __launch_bounds__(256) void k_scatter(const int* __restrict__ eidx,
                                                 int* __restrict__ fill,
                                                 int* __restrict__ perm) {
    int t = blockIdx.x * 256 + threadIdx.x;
    if (t < T_TOK) {
        int e = eidx[t];
        int pos = atomicAdd(&fill[e], 1);
        perm[pos] = t;
    }
}

// ---------------- expert FFN + weighted residual (block per expert-tile) ----------------
__global__ __launch_bounds__(256) void k_expert(const float* __restrict__ y,
                                                const float* __restrict__ x2,
                                                const float* __restrict__ w1,
                                                const float* __restrict__ b1,
                                                const float* __restrict__ w2,
                                                const float* __restrict__ b2,
                                                const int* __restrict__ perm,
                                                const int* __restrict__ counts,
                                                const int* __restrict__ offsets,
                                                const float* __restrict__ wgt,
                                                float* __restrict__ out) {
    int e = blockIdx.x >> 9, tile = blockIdx.x & 511;
    int cnt = counts[e];
    int row0 = tile << 6;
    if (row0 >= cnt) return;
    int off = offsets[e];
    int nr = min(64, cnt - row0);

    __shared__ float yt[64][129];
    __shared__ float ht[64][65];
    __shared__ int rows[64];

    int tid = threadIdx.x, wv = tid >> 6, lane = tid & 63;
    if (tid < 64) rows[tid] = (tid < nr) ? perm[off + row0 + tid] : -1;
    __syncthreads();
    for (int i = tid; i < 64 * DIM; i += 256) {
        int tt = i >> 7, k = i & 127;
        yt[tt][k] = (tt < nr) ? y[(size_t)rows[tt] * DIM + k] : 0.f;
    }
    __syncthreads();

    int c = tid & 127, th = tid >> 7;
    float oacc[32];
    #pragma unroll
    for (int i = 0; i < 32; ++i) oacc[i] = 0.f;
    const float* w2r = w2 + ((size_t)e * DIM + c) * EHID;

    for (int hc = 0; hc < 4; ++hc) {
        // hidden chunk of 64: wave wv computes hh = wv*16..+15 for its lane's token
        for (int jj = 0; jj < 16; ++jj) {
            int hh = wv * 16 + jj;
            int hg = hc * 64 + hh;
            const float* w1r = w1 + ((size_t)e * EHID + hg) * DIM;
            float a = b1[e * EHID + hg];
            #pragma unroll 4
            for (int k = 0; k < DIM; ++k) a = fmaf(yt[lane][k], w1r[k], a);
            ht[lane][hh] = 0.5f * a * (1.f + erff(a * 0.70710678118654752f));  // exact GELU
        }
        __syncthreads();
        #pragma unroll 4
        for (int hh = 0; hh < 64; ++hh) {
            float wv2 = w2r[hc * 64 + hh];
            #pragma unroll
            for (int t2 = 0; t2 < 32; ++t2)
                oacc[t2] = fmaf(ht[th + (t2 << 1)][hh], wv2, oacc[t2]);
        }
        __syncthreads();
    }

    float bb = b2[e * DIM + c];
    for (int t2 = 0; t2 < 32; ++t2) {
        int tt = th + (t2 << 1);
        if (tt < nr) {
            int gtok = rows[tt];
            size_t go = (size_t)gtok * DIM + c;
            out[go] = x2[go] + wgt[gtok] * (oacc[t2] + bb);
        }
    }
}

// ---------------- launch ----------------
extern "C" void kernel_launch(void* const* d_in, const int* in_sizes, int n_in,
                              void* d_out, int out_size, void* d_ws, size_t ws_size,
                              hipStream_t stream) {
    const float* x      = (const float*)d_in[0];
    const float* ln1_g  = (const float*)d_in[1];
    const float* ln1_b  = (const float*)d_in[2];
    const float* w_qkv  = (const float*)d_in[3];
    const float* b_qkv  = (const float*)d_in[4];
    const float* w_proj = (const float*)d_in[5];
    const float* b_proj = (const float*)d_in[6];
    const float* ln2_g  = (const float*)d_in[7];
    const float* ln2_b  = (const float*)d_in[8];
    const float* gate_w = (const float*)d_in[9];
    const float* w1     = (const float*)d_in[10];
    const float* b1     = (const float*)d_in[11];
    const float* w2     = (const float*)d_in[12];
    const float* b2     = (const float*)d_in[13];
    float* out = (float*)d_out;

    // workspace layout (floats/ints)
    float* y    = (float*)d_ws;                  // T*128  (y1 then y2)
    float* x2   = y + (size_t)T_TOK * DIM;       // T*128
    float* wgt  = x2 + (size_t)T_TOK * DIM;      // T
    int* eidx   = (int*)(wgt + T_TOK);           // T
    int* perm   = eidx + T_TOK;                  // T
    int* counts = perm + T_TOK;                  // 16
    int* offs   = counts + NEXP;                 // 16
    int* fill   = offs + NEXP;                   // 16

    k_ln1<<<T_TOK / 4, 256, 0, stream>>>(x, ln1_g, ln1_b, y, counts);
    k_attn<<<NWIN, 256, 0, stream>>>(x, y, w_qkv, b_qkv, w_proj, b_proj, x2);
    k_ln2_gate<<<T_TOK / 4, 256, 0, stream>>>(x2, ln2_g, ln2_b, gate_w, y, eidx, wgt, counts);
    k_scan<<<1, 64, 0, stream>>>(counts, offs, fill);
    k_scatter<<<T_TOK / 256, 256, 0, stream>>>(eidx, fill, perm);
    k_expert<<<NEXP * 512, 256, 0, stream>>>(y, x2, w1, b1, w2, b2, perm, counts, offs, wgt, out);
}

// Round 2
// 580.278 us; speedup vs baseline: 3.5526x; 3.5526x over previous
//
#include <hip/hip_runtime.h>
#include <math.h>

#define T_TOK 32768      // B*N = 2*16384
#define DIM 128
#define NHEADS 4
#define HD 32
#define NEXP 16
#define EHID 256
#define NWIN 512
#define EPS 1e-5f

typedef _Float16 f16x8 __attribute__((ext_vector_type(8)));
typedef float f32x4v __attribute__((ext_vector_type(4)));

#define MFMA16(a, b, c) __builtin_amdgcn_mfma_f32_16x16x32_f16(a, b, c, 0, 0, 0)
#define LO_SCALE 4096.0f
#define LO_INV (1.0f / 4096.0f)

// ---------------- weight fp32 -> fp16 hi/lo conversion + zero counts ----------------
__global__ __launch_bounds__(256) void k_cvt(
    const float* __restrict__ wqkv, const float* __restrict__ wproj,
    const float* __restrict__ w1, const float* __restrict__ w2,
    _Float16* __restrict__ wq_h, _Float16* __restrict__ wq_l,
    _Float16* __restrict__ wp_h, _Float16* __restrict__ wp_l,
    _Float16* __restrict__ w1h, _Float16* __restrict__ w2h,
    int* __restrict__ counts)
{
    int i = blockIdx.x * 256 + threadIdx.x;
    if (blockIdx.x == 0 && threadIdx.x < NEXP) counts[threadIdx.x] = 0;
    if (i < 3 * DIM * DIM) {
        float f = wqkv[i]; _Float16 h = (_Float16)f;
        wq_h[i] = h; wq_l[i] = (_Float16)((f - (float)h) * LO_SCALE);
    }
    if (i < DIM * DIM) {
        float f = wproj[i]; _Float16 h = (_Float16)f;
        wp_h[i] = h; wp_l[i] = (_Float16)((f - (float)h) * LO_SCALE);
    }
    if (i < NEXP * EHID * DIM) {
        w1h[i] = (_Float16)w1[i];
        w2h[i] = (_Float16)w2[i];
    }
}

// ---------------- fused LN1 + windowed attention + proj + residual ----------------
// block = 256 thr (4 waves) per 8x8 window. Full hi/lo split-fp16 MFMA path.
__global__ __launch_bounds__(256) void k_attn(
    const float* __restrict__ x,
    const float* __restrict__ ln_g, const float* __restrict__ ln_b,
    const _Float16* __restrict__ wq_h, const _Float16* __restrict__ wq_l,
    const float* __restrict__ b_qkv,
    const _Float16* __restrict__ wp_h, const _Float16* __restrict__ wp_l,
    const float* __restrict__ b_proj,
    float* __restrict__ x2)
{
    __shared__ _Float16 xwh[64][136], xwl[64][136];   // LN out; reused for O
    __shared__ _Float16 qkh[64][264], qkl[64][264];   // Q(0:128) K(128:256)
    __shared__ _Float16 vth[128][72], vtl[128][72];   // V^T [d][tok]
    __shared__ _Float16 Pmh[64][72], Pml[64][72];     // softmax probs

    int tid = threadIdx.x;
    int wv = tid >> 6, lane = tid & 63;
    int l15 = lane & 15, lg = lane >> 4;
    int wid = blockIdx.x;
    int wb = wid >> 8, wrr = (wid >> 4) & 15, wcc = wid & 15;
    const size_t base = ((size_t)wb * 16384 + (size_t)wrr * 1024 + (size_t)wcc * 8) * DIM;
    // token tt: float offset = base + (tt>>3)*16384 + (tt&7)*128

    // ---- LN1 ----
    {
        int tt = tid >> 2, sub = tid & 3;
        const float* xr = x + base + (size_t)(tt >> 3) * 16384 + (size_t)(tt & 7) * DIM + sub * 32;
        float v[32];
        float s = 0.f, sq = 0.f;
        #pragma unroll
        for (int j = 0; j < 8; ++j) {
            float4 t4 = *(const float4*)(xr + j * 4);
            v[4 * j] = t4.x; v[4 * j + 1] = t4.y; v[4 * j + 2] = t4.z; v[4 * j + 3] = t4.w;
            s += (t4.x + t4.y) + (t4.z + t4.w);
            sq = fmaf(t4.x, t4.x, fmaf(t4.y, t4.y, fmaf(t4.z, t4.z, fmaf(t4.w, t4.w, sq))));
        }
        s += __shfl_xor(s, 1); sq += __shfl_xor(sq, 1);
        s += __shfl_xor(s, 2); sq += __shfl_xor(sq, 2);
        float m = s * (1.f / DIM);
        float var = sq * (1.f / DIM) - m * m;
        float rs = rsqrtf(var + EPS);
        #pragma unroll
        for (int j = 0; j < 32; ++j) {
            int k = sub * 32 + j;
            float a = (v[j] - m) * rs * ln_g[k] + ln_b[k];
            _Float16 h = (_Float16)a;
            xwh[tt][k] = h;
            xwl[tt][k] = (_Float16)((a - (float)h) * LO_SCALE);
        }
    }
    __syncthreads();

    // ---- QKV GEMM: [64,384] = xw[64,128] @ Wqkv^T, split-fp16 3-term ----
    for (int ct = 0; ct < 6; ++ct) {
        int o0 = wv * 96 + ct * 16;
        int o = o0 + l15;
        f16x8 bh[4], bl[4];
        #pragma unroll
        for (int ks = 0; ks < 4; ++ks) {
            size_t wo = (size_t)o * DIM + ks * 32 + lg * 8;
            bh[ks] = *(const f16x8*)(wq_h + wo);
            bl[ks] = *(const f16x8*)(wq_l + wo);
        }
        f32x4v am[4], ac[4];
        #pragma unroll
        for (int rt = 0; rt < 4; ++rt) { am[rt] = 0.0f; ac[rt] = 0.0f; }
        #pragma unroll
        for (int rt = 0; rt < 4; ++rt) {
            int row = rt * 16 + l15;
            #pragma unroll
            for (int ks = 0; ks < 4; ++ks) {
                f16x8 ah = *(const f16x8*)&xwh[row][ks * 32 + lg * 8];
                f16x8 al = *(const f16x8*)&xwl[row][ks * 32 + lg * 8];
                am[rt] = MFMA16(ah, bh[ks], am[rt]);
                ac[rt] = MFMA16(ah, bl[ks], ac[rt]);
                ac[rt] = MFMA16(al, bh[ks], ac[rt]);
            }
        }
        float bias = b_qkv[o];
        #pragma unroll
        for (int rt = 0; rt < 4; ++rt) {
            #pragma unroll
            for (int r = 0; r < 4; ++r) {
                int row = rt * 16 + lg * 4 + r;
                float val = am[rt][r] + ac[rt][r] * LO_INV + bias;
                _Float16 h = (_Float16)val;
                _Float16 lo = (_Float16)((val - (float)h) * LO_SCALE);
                if (o0 < 256) { qkh[row][o] = h; qkl[row][o] = lo; }
                else          { vth[o - 256][row] = h; vtl[o - 256][row] = lo; }
            }
        }
    }
    __syncthreads();

    // ---- per-head: scores -> softmax -> AV ----
    const float scale = 0.17677669529663687f;  // 1/sqrt(32)
    for (int h = 0; h < NHEADS; ++h) {
        int qo = h * HD;
        int ko = 128 + qo;
        f32x4v sm[4], sc2[4];
        f16x8 qah = *(const f16x8*)&qkh[wv * 16 + l15][qo + lg * 8];
        f16x8 qal = *(const f16x8*)&qkl[wv * 16 + l15][qo + lg * 8];
        #pragma unroll
        for (int ct = 0; ct < 4; ++ct) {
            f16x8 kbh = *(const f16x8*)&qkh[ct * 16 + l15][ko + lg * 8];
            f16x8 kbl = *(const f16x8*)&qkl[ct * 16 + l15][ko + lg * 8];
            sm[ct] = 0.0f; sc2[ct] = 0.0f;
            sm[ct] = MFMA16(qah, kbh, sm[ct]);
            sc2[ct] = MFMA16(qah, kbl, sc2[ct]);
            sc2[ct] = MFMA16(qal, kbh, sc2[ct]);
        }
        #pragma unroll
        for (int r = 0; r < 4; ++r) {
            float v0 = (sm[0][r] + sc2[0][r] * LO_INV) * scale;
            float v1 = (sm[1][r] + sc2[1][r] * LO_INV) * scale;
            float v2 = (sm[2][r] + sc2[2][r] * LO_INV) * scale;
            float v3 = (sm[3][r] + sc2[3][r] * LO_INV) * scale;
            float mx = fmaxf(fmaxf(v0, v1), fmaxf(v2, v3));
            mx = fmaxf(mx, __shfl_xor(mx, 1));
            mx = fmaxf(mx, __shfl_xor(mx, 2));
            mx = fmaxf(mx, __shfl_xor(mx, 4));
            mx = fmaxf(mx, __shfl_xor(mx, 8));
            float e0 = expf(v0 - mx), e1 = expf(v1 - mx), e2 = expf(v2 - mx), e3 = expf(v3 - mx);
            float ss = (e0 + e1) + (e2 + e3);
            ss += __shfl_xor(ss, 1); ss += __shfl_xor(ss, 2);
            ss += __shfl_xor(ss, 4); ss += __shfl_xor(ss, 8);
            float inv = 1.f / ss;
            int row = wv * 16 + lg * 4 + r;
            float p0 = e0 * inv, p1 = e1 * inv, p2 = e2 * inv, p3 = e3 * inv;
            _Float16 h0 = (_Float16)p0, h1 = (_Float16)p1, h2 = (_Float16)p2, h3 = (_Float16)p3;
            Pmh[row][l15]      = h0; Pml[row][l15]      = (_Float16)((p0 - (float)h0) * LO_SCALE);
            Pmh[row][16 + l15] = h1; Pml[row][16 + l15] = (_Float16)((p1 - (float)h1) * LO_SCALE);
            Pmh[row][32 + l15] = h2; Pml[row][32 + l15] = (_Float16)((p2 - (float)h2) * LO_SCALE);
            Pmh[row][48 + l15] = h3; Pml[row][48 + l15] = (_Float16)((p3 - (float)h3) * LO_SCALE);
        }
        __syncthreads();
        // AV: O[64,32] = P[64,64] @ V[64,32]
        f32x4v om[2], oc[2];
        om[0] = 0.0f; om[1] = 0.0f; oc[0] = 0.0f; oc[1] = 0.0f;
        #pragma unroll
        for (int ks = 0; ks < 2; ++ks) {
            f16x8 pah = *(const f16x8*)&Pmh[wv * 16 + l15][ks * 32 + lg * 8];
            f16x8 pal = *(const f16x8*)&Pml[wv * 16 + l15][ks * 32 + lg * 8];
            #pragma unroll
            for (int ct = 0; ct < 2; ++ct) {
                f16x8 vbh = *(const f16x8*)&vth[qo + ct * 16 + l15][ks * 32 + lg * 8];
                f16x8 vbl = *(const f16x8*)&vtl[qo + ct * 16 + l15][ks * 32 + lg * 8];
                om[ct] = MFMA16(pah, vbh, om[ct]);
                oc[ct] = MFMA16(pah, vbl, oc[ct]);
                oc[ct] = MFMA16(pal, vbh, oc[ct]);
            }
        }
        #pragma unroll
        for (int ct = 0; ct < 2; ++ct) {
            #pragma unroll
            for (int r = 0; r < 4; ++r) {
                float val = om[ct][r] + oc[ct][r] * LO_INV;
                int row = wv * 16 + lg * 4 + r;
                _Float16 hh = (_Float16)val;
                xwh[row][qo + ct * 16 + l15] = hh;
                xwl[row][qo + ct * 16 + l15] = (_Float16)((val - (float)hh) * LO_SCALE);
            }
        }
        __syncthreads();
    }

    // ---- proj + residual ----
    {
        f32x4v pm[4][2], pc[4][2];
        #pragma unroll
        for (int rt = 0; rt < 4; ++rt) {
            pm[rt][0] = 0.0f; pm[rt][1] = 0.0f; pc[rt][0] = 0.0f; pc[rt][1] = 0.0f;
        }
        #pragma unroll
        for (int ks = 0; ks < 4; ++ks) {
            f16x8 bh[2], bl[2];
            #pragma unroll
            for (int ct = 0; ct < 2; ++ct) {
                int c = wv * 32 + ct * 16 + l15;
                size_t wo = (size_t)c * DIM + ks * 32 + lg * 8;
                bh[ct] = *(const f16x8*)(wp_h + wo);
                bl[ct] = *(const f16x8*)(wp_l + wo);
            }
            #pragma unroll
            for (int rt = 0; rt < 4; ++rt) {
                f16x8 ah = *(const f16x8*)&xwh[rt * 16 + l15][ks * 32 + lg * 8];
                f16x8 al = *(const f16x8*)&xwl[rt * 16 + l15][ks * 32 + lg * 8];
                #pragma unroll
                for (int ct = 0; ct < 2; ++ct) {
                    pm[rt][ct] = MFMA16(ah, bh[ct], pm[rt][ct]);
                    pc[rt][ct] = MFMA16(ah, bl[ct], pc[rt][ct]);
                    pc[rt][ct] = MFMA16(al, bh[ct], pc[rt][ct]);
                }
            }
        }
        #pragma unroll
        for (int rt = 0; rt < 4; ++rt) {
            #pragma unroll
            for (int ct = 0; ct < 2; ++ct) {
                int c = wv * 32 + ct * 16 + l15;
                float bp = b_proj[c];
                #pragma unroll
                for (int r = 0; r < 4; ++r) {
                    int q = rt * 16 + lg * 4 + r;
                    size_t go = base + (size_t)(q >> 3) * 16384 + (size_t)(q & 7) * DIM + c;
                    x2[go] = x[go] + (pm[rt][ct][r] + pc[rt][ct][r] * LO_INV + bp);
                }
            }
        }
    }
}

// ---------------- LN2 + gate + top-1 routing (fp32 gate -> no flips) ----------------
__global__ __launch_bounds__(256) void k_ln2_gate(
    const float* __restrict__ x2, const float* __restrict__ g, const float* __restrict__ b,
    const float* __restrict__ gw, _Float16* __restrict__ y2,
    int* __restrict__ eidx, float* __restrict__ wgt, int* __restrict__ counts)
{
    int tid = threadIdx.x, wv = tid >> 6, lane = tid & 63;
    size_t t = (size_t)blockIdx.x * 4 + wv;
    const float* xr = x2 + t * DIM;
    float2 v = *(const float2*)(xr + lane * 2);
    float s = v.x + v.y, sq = v.x * v.x + v.y * v.y;
    #pragma unroll
    for (int o = 32; o; o >>= 1) { s += __shfl_xor(s, o); sq += __shfl_xor(sq, o); }
    float m = s * (1.f / DIM);
    float var = sq * (1.f / DIM) - m * m;
    float rs = rsqrtf(var + EPS);
    int k = lane * 2;
    float y0 = (v.x - m) * rs * g[k] + b[k];
    float y1 = (v.y - m) * rs * g[k + 1] + b[k + 1];
    y2[t * DIM + k]     = (_Float16)y0;
    y2[t * DIM + k + 1] = (_Float16)y1;

    float lg[NEXP];
    #pragma unroll
    for (int e = 0; e < NEXP; ++e) {
        float p = y0 * gw[e * DIM + k] + y1 * gw[e * DIM + k + 1];
        #pragma unroll
        for (int o = 32; o; o >>= 1) p += __shfl_xor(p, o);
        lg[e] = p;
    }
    float mx = lg[0]; int am = 0;
    #pragma unroll
    for (int e = 1; e < NEXP; ++e) if (lg[e] > mx) { mx = lg[e]; am = e; }
    float ssum = 0.f;
    #pragma unroll
    for (int e = 0; e < NEXP; ++e) ssum += expf(lg[e] - mx);
    float p = 1.f / ssum;
    float w = p / (p + 1e-8f);
    if (lane == 0) {
        eidx[t] = am;
        wgt[t] = w;
        atomicAdd(&counts[am], 1);
    }
}

// ---------------- bucket scan + scatter ----------------
__global__ void k_scan(const int* __restrict__ counts, int* __restrict__ offsets,
                       int* __restrict__ fill) {
    if (threadIdx.x == 0) {
        int off = 0;
        for (int e = 0; e < NEXP; ++e) { offsets[e] = off; fill[e] = off; off += counts[e]; }
    }
}

__global__ __launch_bounds__(256) void k_scatter(const int* __restrict__ eidx,
                                                 int* __restrict__ fill,
                                                 int* __restrict__ perm) {
    int t = blockIdx.x * 256 + threadIdx.x;
    if (t < T_TOK) {
        int e = eidx[t];
        int pos = atomicAdd(&fill[e], 1);
        perm[pos] = t;
    }
}

// ---------------- expert FFN (f16 MFMA) + weighted residual ----------------
__global__ __launch_bounds__(256, 3) void k_expert(
    const _Float16* __restrict__ y2, const float* __restrict__ x2,
    const _Float16* __restrict__ w1h, const float* __restrict__ b1,
    const _Float16* __restrict__ w2h, const float* __restrict__ b2,
    const int* __restrict__ perm, const int* __restrict__ counts,
    const int* __restrict__ offsets, const float* __restrict__ wgt,
    float* __restrict__ out)
{
    __shared__ _Float16 yt[64][136];
    __shared__ _Float16 ht[64][264];
    __shared__ int rows[64];

    int e = blockIdx.x >> 9, tile = blockIdx.x & 511;
    int cnt = counts[e];
    int row0 = tile << 6;
    if (row0 >= cnt) return;
    int off = offsets[e], nr = min(64, cnt - row0);
    int tid = threadIdx.x, wv = tid >> 6, lane = tid & 63;
    int l15 = lane & 15, lg = lane >> 4;

    if (tid < 64) rows[tid] = (tid < nr) ? perm[off + row0 + tid] : 0;
    __syncthreads();
    f16x8 vz = (_Float16)0.0f;
    for (int i = tid; i < 1024; i += 256) {
        int tt = i >> 4, k = (i & 15) * 8;
        f16x8 val = vz;
        if (tt < nr) val = *(const f16x8*)(y2 + (size_t)rows[tt] * DIM + k);
        *(f16x8*)&yt[tt][k] = val;
    }
    __syncthreads();

    // GEMM1: h = GELU(yt @ w1e^T + b1)  [64,256], wave -> 64 hid cols
    for (int ct = 0; ct < 4; ++ct) {
        int hid = wv * 64 + ct * 16 + l15;
        f16x8 bf[4];
        #pragma unroll
        for (int ks = 0; ks < 4; ++ks)
            bf[ks] = *(const f16x8*)(w1h + ((size_t)e * EHID + hid) * DIM + ks * 32 + lg * 8);
        f32x4v acc[4];
        #pragma unroll
        for (int rt = 0; rt < 4; ++rt) acc[rt] = 0.0f;
        #pragma unroll
        for (int rt = 0; rt < 4; ++rt)
            #pragma unroll
            for (int ks = 0; ks < 4; ++ks)
                acc[rt] = MFMA16(*(const f16x8*)&yt[rt * 16 + l15][ks * 32 + lg * 8], bf[ks], acc[rt]);
        float bb = b1[e * EHID + hid];
        #pragma unroll
        for (int rt = 0; rt < 4; ++rt) {
            #pragma unroll
            for (int r = 0; r < 4; ++r) {
                float a = acc[rt][r] + bb;
                float gl = 0.5f * a * (1.f + erff(a * 0.70710678118654752f));
                ht[rt * 16 + lg * 4 + r][hid] = (_Float16)gl;
            }
        }
    }
    __syncthreads();

    // GEMM2: o = ht @ w2e^T  [64,128], wave -> 32 out cols
    {
        f32x4v acc[4][2];
        #pragma unroll
        for (int rt = 0; rt < 4; ++rt) { acc[rt][0] = 0.0f; acc[rt][1] = 0.0f; }
        for (int ks = 0; ks < 8; ++ks) {
            f16x8 bf[2];
            #pragma unroll
            for (int ct = 0; ct < 2; ++ct) {
                int c = wv * 32 + ct * 16 + l15;
                bf[ct] = *(const f16x8*)(w2h + ((size_t)e * DIM + c) * EHID + ks * 32 + lg * 8);
            }
            #pragma unroll
            for (int rt = 0; rt < 4; ++rt) {
                f16x8 af = *(const f16x8*)&ht[rt * 16 + l15][ks * 32 + lg * 8];
                #pragma unroll
                for (int ct = 0; ct < 2; ++ct)
                    acc[rt][ct] = MFMA16(af, bf[ct], acc[rt][ct]);
            }
        }
        #pragma unroll
        for (int rt = 0; rt < 4; ++rt) {
            #pragma unroll
            for (int ct = 0; ct < 2; ++ct) {
                int c = wv * 32 + ct * 16 + l15;
                float bb = b2[e * DIM + c];
                #pragma unroll
                for (int r = 0; r < 4; ++r) {
                    int tt = rt * 16 + lg * 4 + r;
                    if (tt < nr) {
                        int gtok = rows[tt];
                        size_t go = (size_t)gtok * DIM + c;
                        out[go] = x2[go] + wgt[gtok] * (acc[rt][ct][r] + bb);
                    }
                }
            }
        }
    }
}

// ---------------- launch ----------------
extern "C" void kernel_launch(void* const* d_in, const int* in_sizes, int n_in,
                              void* d_out, int out_size, void* d_ws, size_t ws_size,
                              hipStream_t stream) {
    const float* x      = (const float*)d_in[0];
    const float* ln1_g  = (const float*)d_in[1];
    const float* ln1_b  = (const float*)d_in[2];
    const float* w_qkv  = (const float*)d_in[3];
    const float* b_qkv  = (const float*)d_in[4];
    const float* w_proj = (const float*)d_in[5];
    const float* b_proj = (const float*)d_in[6];
    const float* ln2_g  = (const float*)d_in[7];
    const float* ln2_b  = (const float*)d_in[8];
    const float* gate_w = (const float*)d_in[9];
    const float* w1     = (const float*)d_in[10];
    const float* b1     = (const float*)d_in[11];
    const float* w2     = (const float*)d_in[12];
    const float* b2     = (const float*)d_in[13];
    float* out = (float*)d_out;

    // workspace layout (all offsets 16B-aligned)
    char* p = (char*)d_ws;
    float* x2 = (float*)p;                 p += (size_t)T_TOK * DIM * 4;   // 16 MB
    _Float16* y2 = (_Float16*)p;           p += (size_t)T_TOK * DIM * 2;   // 8 MB
    _Float16* wq_h = (_Float16*)p;         p += 3 * DIM * DIM * 2;
    _Float16* wq_l = (_Float16*)p;         p += 3 * DIM * DIM * 2;
    _Float16* wp_h = (_Float16*)p;         p += DIM * DIM * 2;
    _Float16* wp_l = (_Float16*)p;         p += DIM * DIM * 2;
    _Float16* w1h = (_Float16*)p;          p += NEXP * EHID * DIM * 2;
    _Float16* w2h = (_Float16*)p;          p += NEXP * EHID * DIM * 2;
    float* wgt = (float*)p;                p += T_TOK * 4;
    int* eidx = (int*)p;                   p += T_TOK * 4;
    int* perm = (int*)p;                   p += T_TOK * 4;
    int* counts = (int*)p;                 p += 16 * 4;
    int* offs = (int*)p;                   p += 16 * 4;
    int* fill = (int*)p;                   p += 16 * 4;

    k_cvt<<<2048, 256, 0, stream>>>(w_qkv, w_proj, w1, w2, wq_h, wq_l, wp_h, wp_l,
                                    w1h, w2h, counts);
    k_attn<<<NWIN, 256, 0, stream>>>(x, ln1_g, ln1_b, wq_h, wq_l, b_qkv,
                                     wp_h, wp_l, b_proj, x2);
    k_ln2_gate<<<T_TOK / 4, 256, 0, stream>>>(x2, ln2_g, ln2_b, gate_w, y2, eidx, wgt, counts);
    k_scan<<<1, 64, 0, stream>>>(counts, offs, fill);
    k_scatter<<<T_TOK / 256, 256, 0, stream>>>(eidx, fill, perm);
    k_expert<<<NEXP * 512, 256, 0, stream>>>(y2, x2, w1h, b1, w2h, b2, perm, counts,
                                             offs, wgt, out);
}

// Round 3
// 133.990 us; speedup vs baseline: 15.3853x; 4.3308x over previous
//
#include <hip/hip_runtime.h>
#include <math.h>

#define T_TOK 32768      // B*N = 2*16384
#define DIM 128
#define NHEADS 4
#define HD 32
#define NEXP 16
#define EHID 256
#define NWIN 512
#define EPS 1e-5f
#define CPAD 16          // counter padding: 64B apart

typedef _Float16 f16x8 __attribute__((ext_vector_type(8)));
typedef float f32x4v __attribute__((ext_vector_type(4)));

#define MFMA16(a, b, c) __builtin_amdgcn_mfma_f32_16x16x32_f16(a, b, c, 0, 0, 0)
#define LO_SCALE 4096.0f
#define LO_INV (1.0f / 4096.0f)

// ---------------- weight fp32 -> fp16 hi/lo conversion + zero counters ----------------
__global__ __launch_bounds__(256) void k_cvt(
    const float* __restrict__ wqkv, const float* __restrict__ wproj,
    const float* __restrict__ w1, const float* __restrict__ w2,
    _Float16* __restrict__ wq_h, _Float16* __restrict__ wq_l,
    _Float16* __restrict__ wp_h, _Float16* __restrict__ wp_l,
    _Float16* __restrict__ w1h, _Float16* __restrict__ w2h,
    int* __restrict__ counts)
{
    int i = blockIdx.x * 256 + threadIdx.x;
    if (blockIdx.x == 0 && threadIdx.x < NEXP * CPAD) counts[threadIdx.x] = 0;
    if (i < 3 * DIM * DIM) {
        float f = wqkv[i]; _Float16 h = (_Float16)f;
        wq_h[i] = h; wq_l[i] = (_Float16)((f - (float)h) * LO_SCALE);
    }
    if (i < DIM * DIM) {
        float f = wproj[i]; _Float16 h = (_Float16)f;
        wp_h[i] = h; wp_l[i] = (_Float16)((f - (float)h) * LO_SCALE);
    }
    if (i < NEXP * EHID * DIM) {
        w1h[i] = (_Float16)w1[i];
        w2h[i] = (_Float16)w2[i];
    }
}

// ---------------- fused LN1 + windowed attention + proj + residual ----------------
__global__ __launch_bounds__(256) void k_attn(
    const float* __restrict__ x,
    const float* __restrict__ ln_g, const float* __restrict__ ln_b,
    const _Float16* __restrict__ wq_h, const _Float16* __restrict__ wq_l,
    const float* __restrict__ b_qkv,
    const _Float16* __restrict__ wp_h, const _Float16* __restrict__ wp_l,
    const float* __restrict__ b_proj,
    float* __restrict__ x2)
{
    __shared__ _Float16 xwh[64][136], xwl[64][136];   // LN out; reused for O
    __shared__ _Float16 qkh[64][264], qkl[64][264];   // Q(0:128) K(128:256)
    __shared__ _Float16 vth[128][72], vtl[128][72];   // V^T [d][tok]
    __shared__ _Float16 Pmh[64][72], Pml[64][72];     // softmax probs

    int tid = threadIdx.x;
    int wv = tid >> 6, lane = tid & 63;
    int l15 = lane & 15, lg = lane >> 4;
    int wid = blockIdx.x;
    int wb = wid >> 8, wrr = (wid >> 4) & 15, wcc = wid & 15;
    const size_t base = ((size_t)wb * 16384 + (size_t)wrr * 1024 + (size_t)wcc * 8) * DIM;

    // ---- LN1 ----
    {
        int tt = tid >> 2, sub = tid & 3;
        const float* xr = x + base + (size_t)(tt >> 3) * 16384 + (size_t)(tt & 7) * DIM + sub * 32;
        float v[32];
        float s = 0.f, sq = 0.f;
        #pragma unroll
        for (int j = 0; j < 8; ++j) {
            float4 t4 = *(const float4*)(xr + j * 4);
            v[4 * j] = t4.x; v[4 * j + 1] = t4.y; v[4 * j + 2] = t4.z; v[4 * j + 3] = t4.w;
            s += (t4.x + t4.y) + (t4.z + t4.w);
            sq = fmaf(t4.x, t4.x, fmaf(t4.y, t4.y, fmaf(t4.z, t4.z, fmaf(t4.w, t4.w, sq))));
        }
        s += __shfl_xor(s, 1); sq += __shfl_xor(sq, 1);
        s += __shfl_xor(s, 2); sq += __shfl_xor(sq, 2);
        float m = s * (1.f / DIM);
        float var = sq * (1.f / DIM) - m * m;
        float rs = rsqrtf(var + EPS);
        #pragma unroll
        for (int j = 0; j < 32; ++j) {
            int k = sub * 32 + j;
            float a = (v[j] - m) * rs * ln_g[k] + ln_b[k];
            _Float16 h = (_Float16)a;
            xwh[tt][k] = h;
            xwl[tt][k] = (_Float16)((a - (float)h) * LO_SCALE);
        }
    }
    __syncthreads();

    // ---- QKV GEMM: [64,384] = xw[64,128] @ Wqkv^T, split-fp16 3-term ----
    for (int ct = 0; ct < 6; ++ct) {
        int o0 = wv * 96 + ct * 16;
        int o = o0 + l15;
        f16x8 bh[4], bl[4];
        #pragma unroll
        for (int ks = 0; ks < 4; ++ks) {
            size_t wo = (size_t)o * DIM + ks * 32 + lg * 8;
            bh[ks] = *(const f16x8*)(wq_h + wo);
            bl[ks] = *(const f16x8*)(wq_l + wo);
        }
        f32x4v am[4], ac[4];
        #pragma unroll
        for (int rt = 0; rt < 4; ++rt) { am[rt] = 0.0f; ac[rt] = 0.0f; }
        #pragma unroll
        for (int rt = 0; rt < 4; ++rt) {
            int row = rt * 16 + l15;
            #pragma unroll
            for (int ks = 0; ks < 4; ++ks) {
                f16x8 ah = *(const f16x8*)&xwh[row][ks * 32 + lg * 8];
                f16x8 al = *(const f16x8*)&xwl[row][ks * 32 + lg * 8];
                am[rt] = MFMA16(ah, bh[ks], am[rt]);
                ac[rt] = MFMA16(ah, bl[ks], ac[rt]);
                ac[rt] = MFMA16(al, bh[ks], ac[rt]);
            }
        }
        float bias = b_qkv[o];
        #pragma unroll
        for (int rt = 0; rt < 4; ++rt) {
            #pragma unroll
            for (int r = 0; r < 4; ++r) {
                int row = rt * 16 + lg * 4 + r;
                float val = am[rt][r] + ac[rt][r] * LO_INV + bias;
                _Float16 h = (_Float16)val;
                _Float16 lo = (_Float16)((val - (float)h) * LO_SCALE);
                if (o0 < 256) { qkh[row][o] = h; qkl[row][o] = lo; }
                else          { vth[o - 256][row] = h; vtl[o - 256][row] = lo; }
            }
        }
    }
    __syncthreads();

    // ---- per-head: scores -> softmax -> AV ----
    const float scale = 0.17677669529663687f;  // 1/sqrt(32)
    for (int h = 0; h < NHEADS; ++h) {
        int qo = h * HD;
        int ko = 128 + qo;
        f32x4v sm[4], sc2[4];
        f16x8 qah = *(const f16x8*)&qkh[wv * 16 + l15][qo + lg * 8];
        f16x8 qal = *(const f16x8*)&qkl[wv * 16 + l15][qo + lg * 8];
        #pragma unroll
        for (int ct = 0; ct < 4; ++ct) {
            f16x8 kbh = *(const f16x8*)&qkh[ct * 16 + l15][ko + lg * 8];
            f16x8 kbl = *(const f16x8*)&qkl[ct * 16 + l15][ko + lg * 8];
            sm[ct] = 0.0f; sc2[ct] = 0.0f;
            sm[ct] = MFMA16(qah, kbh, sm[ct]);
            sc2[ct] = MFMA16(qah, kbl, sc2[ct]);
            sc2[ct] = MFMA16(qal, kbh, sc2[ct]);
        }
        #pragma unroll
        for (int r = 0; r < 4; ++r) {
            float v0 = (sm[0][r] + sc2[0][r] * LO_INV) * scale;
            float v1 = (sm[1][r] + sc2[1][r] * LO_INV) * scale;
            float v2 = (sm[2][r] + sc2[2][r] * LO_INV) * scale;
            float v3 = (sm[3][r] + sc2[3][r] * LO_INV) * scale;
            float mx = fmaxf(fmaxf(v0, v1), fmaxf(v2, v3));
            mx = fmaxf(mx, __shfl_xor(mx, 1));
            mx = fmaxf(mx, __shfl_xor(mx, 2));
            mx = fmaxf(mx, __shfl_xor(mx, 4));
            mx = fmaxf(mx, __shfl_xor(mx, 8));
            float e0 = expf(v0 - mx), e1 = expf(v1 - mx), e2 = expf(v2 - mx), e3 = expf(v3 - mx);
            float ss = (e0 + e1) + (e2 + e3);
            ss += __shfl_xor(ss, 1); ss += __shfl_xor(ss, 2);
            ss += __shfl_xor(ss, 4); ss += __shfl_xor(ss, 8);
            float inv = 1.f / ss;
            int row = wv * 16 + lg * 4 + r;
            float p0 = e0 * inv, p1 = e1 * inv, p2 = e2 * inv, p3 = e3 * inv;
            _Float16 h0 = (_Float16)p0, h1 = (_Float16)p1, h2 = (_Float16)p2, h3 = (_Float16)p3;
            Pmh[row][l15]      = h0; Pml[row][l15]      = (_Float16)((p0 - (float)h0) * LO_SCALE);
            Pmh[row][16 + l15] = h1; Pml[row][16 + l15] = (_Float16)((p1 - (float)h1) * LO_SCALE);
            Pmh[row][32 + l15] = h2; Pml[row][32 + l15] = (_Float16)((p2 - (float)h2) * LO_SCALE);
            Pmh[row][48 + l15] = h3; Pml[row][48 + l15] = (_Float16)((p3 - (float)h3) * LO_SCALE);
        }
        __syncthreads();
        // AV: O[64,32] = P[64,64] @ V[64,32]
        f32x4v om[2], oc[2];
        om[0] = 0.0f; om[1] = 0.0f; oc[0] = 0.0f; oc[1] = 0.0f;
        #pragma unroll
        for (int ks = 0; ks < 2; ++ks) {
            f16x8 pah = *(const f16x8*)&Pmh[wv * 16 + l15][ks * 32 + lg * 8];
            f16x8 pal = *(const f16x8*)&Pml[wv * 16 + l15][ks * 32 + lg * 8];
            #pragma unroll
            for (int ct = 0; ct < 2; ++ct) {
                f16x8 vbh = *(const f16x8*)&vth[qo + ct * 16 + l15][ks * 32 + lg * 8];
                f16x8 vbl = *(const f16x8*)&vtl[qo + ct * 16 + l15][ks * 32 + lg * 8];
                om[ct] = MFMA16(pah, vbh, om[ct]);
                oc[ct] = MFMA16(pah, vbl, oc[ct]);
                oc[ct] = MFMA16(pal, vbh, oc[ct]);
            }
        }
        #pragma unroll
        for (int ct = 0; ct < 2; ++ct) {
            #pragma unroll
            for (int r = 0; r < 4; ++r) {
                float val = om[ct][r] + oc[ct][r] * LO_INV;
                int row = wv * 16 + lg * 4 + r;
                _Float16 hh = (_Float16)val;
                xwh[row][qo + ct * 16 + l15] = hh;
                xwl[row][qo + ct * 16 + l15] = (_Float16)((val - (float)hh) * LO_SCALE);
            }
        }
        __syncthreads();
    }

    // ---- proj + residual ----
    {
        f32x4v pm[4][2], pc[4][2];
        #pragma unroll
        for (int rt = 0; rt < 4; ++rt) {
            pm[rt][0] = 0.0f; pm[rt][1] = 0.0f; pc[rt][0] = 0.0f; pc[rt][1] = 0.0f;
        }
        #pragma unroll
        for (int ks = 0; ks < 4; ++ks) {
            f16x8 bh[2], bl[2];
            #pragma unroll
            for (int ct = 0; ct < 2; ++ct) {
                int c = wv * 32 + ct * 16 + l15;
                size_t wo = (size_t)c * DIM + ks * 32 + lg * 8;
                bh[ct] = *(const f16x8*)(wp_h + wo);
                bl[ct] = *(const f16x8*)(wp_l + wo);
            }
            #pragma unroll
            for (int rt = 0; rt < 4; ++rt) {
                f16x8 ah = *(const f16x8*)&xwh[rt * 16 + l15][ks * 32 + lg * 8];
                f16x8 al = *(const f16x8*)&xwl[rt * 16 + l15][ks * 32 + lg * 8];
                #pragma unroll
                for (int ct = 0; ct < 2; ++ct) {
                    pm[rt][ct] = MFMA16(ah, bh[ct], pm[rt][ct]);
                    pc[rt][ct] = MFMA16(ah, bl[ct], pc[rt][ct]);
                    pc[rt][ct] = MFMA16(al, bh[ct], pc[rt][ct]);
                }
            }
        }
        #pragma unroll
        for (int rt = 0; rt < 4; ++rt) {
            #pragma unroll
            for (int ct = 0; ct < 2; ++ct) {
                int c = wv * 32 + ct * 16 + l15;
                float bp = b_proj[c];
                #pragma unroll
                for (int r = 0; r < 4; ++r) {
                    int q = rt * 16 + lg * 4 + r;
                    size_t go = base + (size_t)(q >> 3) * 16384 + (size_t)(q & 7) * DIM + c;
                    x2[go] = x[go] + (pm[rt][ct][r] + pc[rt][ct][r] * LO_INV + bp);
                }
            }
        }
    }
}

// ---------------- LN2 + gate + routing + scatter (block per 64 tokens) ----------------
__global__ __launch_bounds__(256) void k_ln2_gate(
    const float* __restrict__ x2, const float* __restrict__ g, const float* __restrict__ b,
    const float* __restrict__ gw, _Float16* __restrict__ y2,
    float* __restrict__ wgt, int* __restrict__ perm, int* __restrict__ counts)
{
    __shared__ float yt[64][129];    // fp32 LN output (conflict-free stride)
    __shared__ float lgs[64][17];    // gate logits
    int tid = threadIdx.x;
    size_t t0 = (size_t)blockIdx.x * 64;

    // ---- LN2: 4 threads per token ----
    {
        int tt = tid >> 2, sub = tid & 3;
        const float* xr = x2 + (t0 + tt) * DIM + sub * 32;
        float v[32];
        float s = 0.f, sq = 0.f;
        #pragma unroll
        for (int j = 0; j < 8; ++j) {
            float4 t4 = *(const float4*)(xr + j * 4);
            v[4 * j] = t4.x; v[4 * j + 1] = t4.y; v[4 * j + 2] = t4.z; v[4 * j + 3] = t4.w;
            s += (t4.x + t4.y) + (t4.z + t4.w);
            sq = fmaf(t4.x, t4.x, fmaf(t4.y, t4.y, fmaf(t4.z, t4.z, fmaf(t4.w, t4.w, sq))));
        }
        s += __shfl_xor(s, 1); sq += __shfl_xor(sq, 1);
        s += __shfl_xor(s, 2); sq += __shfl_xor(sq, 2);
        float m = s * (1.f / DIM);
        float var = sq * (1.f / DIM) - m * m;
        float rs = rsqrtf(var + EPS);
        _Float16 hh[32];
        #pragma unroll
        for (int j = 0; j < 32; ++j) {
            int k = sub * 32 + j;
            float a = (v[j] - m) * rs * g[k] + b[k];
            yt[tt][k] = a;
            hh[j] = (_Float16)a;
        }
        #pragma unroll
        for (int j = 0; j < 4; ++j)
            *(f16x8*)(y2 + (t0 + tt) * DIM + sub * 32 + j * 8) = *(const f16x8*)&hh[j * 8];
    }
    __syncthreads();

    // ---- gate logits: thread -> (token = tid&63, experts eg*4..eg*4+3), fp32 ----
    {
        int tt = tid & 63, eg = tid >> 6;
        const float* g0 = gw + (eg * 4 + 0) * DIM;
        const float* g1 = gw + (eg * 4 + 1) * DIM;
        const float* g2 = gw + (eg * 4 + 2) * DIM;
        const float* g3 = gw + (eg * 4 + 3) * DIM;
        float a0 = 0.f, a1 = 0.f, a2 = 0.f, a3 = 0.f;
        #pragma unroll 8
        for (int k = 0; k < DIM; ++k) {
            float yv = yt[tt][k];
            a0 = fmaf(yv, g0[k], a0);
            a1 = fmaf(yv, g1[k], a1);
            a2 = fmaf(yv, g2[k], a2);
            a3 = fmaf(yv, g3[k], a3);
        }
        lgs[tt][eg * 4 + 0] = a0;
        lgs[tt][eg * 4 + 1] = a1;
        lgs[tt][eg * 4 + 2] = a2;
        lgs[tt][eg * 4 + 3] = a3;
    }
    __syncthreads();

    // ---- routing + ballot rank + scatter (wave 0, lane = token) ----
    if (tid < 64) {
        float mx = -1e30f; int am = 0;
        #pragma unroll
        for (int e = 0; e < NEXP; ++e) {
            float v = lgs[tid][e];
            if (v > mx) { mx = v; am = e; }
        }
        float ss = 0.f;
        #pragma unroll
        for (int e = 0; e < NEXP; ++e) ss += expf(lgs[tid][e] - mx);
        float p = 1.f / ss;
        wgt[t0 + tid] = p / (p + 1e-8f);

        int myrank = 0, mycnt = 0;
        #pragma unroll
        for (int e = 0; e < NEXP; ++e) {
            unsigned long long mask = __ballot(am == e);
            if (am == e) myrank = (int)__popcll(mask & ((1ull << tid) - 1));
            if (tid == e) mycnt = (int)__popcll(mask);
        }
        int base = 0;
        if (tid < NEXP) base = atomicAdd(&counts[tid * CPAD], mycnt);
        base = __shfl(base, am);
        perm[(size_t)am * T_TOK + base + myrank] = (int)(t0 + tid);
    }
}

// ---------------- expert FFN (f16 MFMA) + weighted residual ----------------
__global__ __launch_bounds__(256, 3) void k_expert(
    const _Float16* __restrict__ y2, const float* __restrict__ x2,
    const _Float16* __restrict__ w1h, const float* __restrict__ b1,
    const _Float16* __restrict__ w2h, const float* __restrict__ b2,
    const int* __restrict__ perm, const int* __restrict__ counts,
    const float* __restrict__ wgt, float* __restrict__ out)
{
    __shared__ _Float16 yt[64][136];
    __shared__ _Float16 ht[64][264];
    __shared__ int rows[64];

    int e = blockIdx.x >> 9, tile = blockIdx.x & 511;
    int cnt = counts[e * CPAD];
    int row0 = tile << 6;
    if (row0 >= cnt) return;
    int nr = min(64, cnt - row0);
    int tid = threadIdx.x, wv = tid >> 6, lane = tid & 63;
    int l15 = lane & 15, lg = lane >> 4;

    if (tid < 64) rows[tid] = (tid < nr) ? perm[(size_t)e * T_TOK + row0 + tid] : 0;
    __syncthreads();
    f16x8 vz = (_Float16)0.0f;
    for (int i = tid; i < 1024; i += 256) {
        int tt = i >> 4, k = (i & 15) * 8;
        f16x8 val = vz;
        if (tt < nr) val = *(const f16x8*)(y2 + (size_t)rows[tt] * DIM + k);
        *(f16x8*)&yt[tt][k] = val;
    }
    __syncthreads();

    // GEMM1: h = GELU(yt @ w1e^T + b1)  [64,256], wave -> 64 hid cols
    for (int ct = 0; ct < 4; ++ct) {
        int hid = wv * 64 + ct * 16 + l15;
        f16x8 bf[4];
        #pragma unroll
        for (int ks = 0; ks < 4; ++ks)
            bf[ks] = *(const f16x8*)(w1h + ((size_t)e * EHID + hid) * DIM + ks * 32 + lg * 8);
        f32x4v acc[4];
        #pragma unroll
        for (int rt = 0; rt < 4; ++rt) acc[rt] = 0.0f;
        #pragma unroll
        for (int rt = 0; rt < 4; ++rt)
            #pragma unroll
            for (int ks = 0; ks < 4; ++ks)
                acc[rt] = MFMA16(*(const f16x8*)&yt[rt * 16 + l15][ks * 32 + lg * 8], bf[ks], acc[rt]);
        float bb = b1[e * EHID + hid];
        #pragma unroll
        for (int rt = 0; rt < 4; ++rt) {
            #pragma unroll
            for (int r = 0; r < 4; ++r) {
                float a = acc[rt][r] + bb;
                float gl = 0.5f * a * (1.f + erff(a * 0.70710678118654752f));
                ht[rt * 16 + lg * 4 + r][hid] = (_Float16)gl;
            }
        }
    }
    __syncthreads();

    // GEMM2: o = ht @ w2e^T  [64,128], wave -> 32 out cols
    {
        f32x4v acc[4][2];
        #pragma unroll
        for (int rt = 0; rt < 4; ++rt) { acc[rt][0] = 0.0f; acc[rt][1] = 0.0f; }
        for (int ks = 0; ks < 8; ++ks) {
            f16x8 bf[2];
            #pragma unroll
            for (int ct = 0; ct < 2; ++ct) {
                int c = wv * 32 + ct * 16 + l15;
                bf[ct] = *(const f16x8*)(w2h + ((size_t)e * DIM + c) * EHID + ks * 32 + lg * 8);
            }
            #pragma unroll
            for (int rt = 0; rt < 4; ++rt) {
                f16x8 af = *(const f16x8*)&ht[rt * 16 + l15][ks * 32 + lg * 8];
                #pragma unroll
                for (int ct = 0; ct < 2; ++ct)
                    acc[rt][ct] = MFMA16(af, bf[ct], acc[rt][ct]);
            }
        }
        #pragma unroll
        for (int rt = 0; rt < 4; ++rt) {
            #pragma unroll
            for (int ct = 0; ct < 2; ++ct) {
                int c = wv * 32 + ct * 16 + l15;
                float bb = b2[e * DIM + c];
                #pragma unroll
                for (int r = 0; r < 4; ++r) {
                    int tt = rt * 16 + lg * 4 + r;
                    if (tt < nr) {
                        int gtok = rows[tt];
                        size_t go = (size_t)gtok * DIM + c;
                        out[go] = x2[go] + wgt[gtok] * (acc[rt][ct][r] + bb);
                    }
                }
            }
        }
    }
}

// ---------------- launch ----------------
extern "C" void kernel_launch(void* const* d_in, const int* in_sizes, int n_in,
                              void* d_out, int out_size, void* d_ws, size_t ws_size,
                              hipStream_t stream) {
    const float* x      = (const float*)d_in[0];
    const float* ln1_g  = (const float*)d_in[1];
    const float* ln1_b  = (const float*)d_in[2];
    const float* w_qkv  = (const float*)d_in[3];
    const float* b_qkv  = (const float*)d_in[4];
    const float* w_proj = (const float*)d_in[5];
    const float* b_proj = (const float*)d_in[6];
    const float* ln2_g  = (const float*)d_in[7];
    const float* ln2_b  = (const float*)d_in[8];
    const float* gate_w = (const float*)d_in[9];
    const float* w1     = (const float*)d_in[10];
    const float* b1     = (const float*)d_in[11];
    const float* w2     = (const float*)d_in[12];
    const float* b2     = (const float*)d_in[13];
    float* out = (float*)d_out;

    // workspace layout (all offsets 16B-aligned)
    char* p = (char*)d_ws;
    float* x2 = (float*)p;                 p += (size_t)T_TOK * DIM * 4;       // 16 MB
    _Float16* y2 = (_Float16*)p;           p += (size_t)T_TOK * DIM * 2;       // 8 MB
    _Float16* wq_h = (_Float16*)p;         p += 3 * DIM * DIM * 2;
    _Float16* wq_l = (_Float16*)p;         p += 3 * DIM * DIM * 2;
    _Float16* wp_h = (_Float16*)p;         p += DIM * DIM * 2;
    _Float16* wp_l = (_Float16*)p;         p += DIM * DIM * 2;
    _Float16* w1h = (_Float16*)p;          p += NEXP * EHID * DIM * 2;
    _Float16* w2h = (_Float16*)p;          p += NEXP * EHID * DIM * 2;
    float* wgt = (float*)p;                p += T_TOK * 4;
    int* perm = (int*)p;                   p += (size_t)NEXP * T_TOK * 4;      // 2 MB
    int* counts = (int*)p;                 p += NEXP * CPAD * 4;

    k_cvt<<<2048, 256, 0, stream>>>(w_qkv, w_proj, w1, w2, wq_h, wq_l, wp_h, wp_l,
                                    w1h, w2h, counts);
    k_attn<<<NWIN, 256, 0, stream>>>(x, ln1_g, ln1_b, wq_h, wq_l, b_qkv,
                                     wp_h, wp_l, b_proj, x2);
    k_ln2_gate<<<T_TOK / 64, 256, 0, stream>>>(x2, ln2_g, ln2_b, gate_w, y2, wgt, perm, counts);
    k_expert<<<NEXP * 512, 256, 0, stream>>>(y2, x2, w1h, b1, w2h, b2, perm, counts, wgt, out);
}

// Round 4
// 129.624 us; speedup vs baseline: 15.9035x; 1.0337x over previous
//
#include <hip/hip_runtime.h>
#include <math.h>

#define T_TOK 32768      // B*N = 2*16384
#define DIM 128
#define NHEADS 4
#define HD 32
#define NEXP 16
#define EHID 256
#define NWIN 512
#define EPS 1e-5f
#define CPAD 16          // counter padding: 64B apart

typedef _Float16 f16x8 __attribute__((ext_vector_type(8)));
typedef float f32x4v __attribute__((ext_vector_type(4)));

#define MFMA16(a, b, c) __builtin_amdgcn_mfma_f32_16x16x32_f16(a, b, c, 0, 0, 0)
#define LO_SCALE 4096.0f
#define LO_INV (1.0f / 4096.0f)

// swizzled f16 index into a [R][128] tile: byte=r*256+c*2, 16B-chunk ^= r&7
__device__ __forceinline__ int sw128(int r, int c) {
    return r * 128 + (((c >> 3) ^ (r & 7)) << 3) + (c & 7);
}
// swizzled f16 index into a [R][64] tile: byte=r*128+c*2
__device__ __forceinline__ int sw64(int r, int c) {
    return r * 64 + (((c >> 3) ^ (r & 7)) << 3) + (c & 7);
}

// ---------------- weight fp32 -> fp16 hi/lo conversion + zero counters ----------------
__global__ __launch_bounds__(256) void k_cvt(
    const float* __restrict__ wqkv, const float* __restrict__ wproj,
    const float* __restrict__ w1, const float* __restrict__ w2,
    _Float16* __restrict__ wq_h, _Float16* __restrict__ wq_l,
    _Float16* __restrict__ wp_h, _Float16* __restrict__ wp_l,
    _Float16* __restrict__ w1h, _Float16* __restrict__ w2h,
    int* __restrict__ counts)
{
    int i = blockIdx.x * 256 + threadIdx.x;
    if (blockIdx.x == 0 && threadIdx.x < NEXP * CPAD) counts[threadIdx.x] = 0;
    if (i < 3 * DIM * DIM) {
        float f = wqkv[i]; _Float16 h = (_Float16)f;
        wq_h[i] = h; wq_l[i] = (_Float16)((f - (float)h) * LO_SCALE);
    }
    if (i < DIM * DIM) {
        float f = wproj[i]; _Float16 h = (_Float16)f;
        wp_h[i] = h; wp_l[i] = (_Float16)((f - (float)h) * LO_SCALE);
    }
    if (i < NEXP * EHID * DIM) {
        w1h[i] = (_Float16)w1[i];
        w2h[i] = (_Float16)w2[i];
    }
}

// ---------------- fused LN1 + windowed attention + proj + residual ----------------
// 512 threads (8 waves) per 8x8 window. hi/lo split-fp16 MFMA throughout.
// LDS 128KB, XOR-swizzled, 5 barriers.
__global__ __launch_bounds__(512) void k_attn(
    const float* __restrict__ x,
    const float* __restrict__ ln_g, const float* __restrict__ ln_b,
    const _Float16* __restrict__ wq_h, const _Float16* __restrict__ wq_l,
    const float* __restrict__ b_qkv,
    const _Float16* __restrict__ wp_h, const _Float16* __restrict__ wp_l,
    const float* __restrict__ b_proj,
    float* __restrict__ x2)
{
    __shared__ _Float16 xoh[64 * 128], xol[64 * 128];  // LN out; reused as O
    __shared__ _Float16 qh[64 * 128],  ql[64 * 128];   // Q ; later P(h0) at 0, P(h1) at 4096
    __shared__ _Float16 kh[64 * 128],  kl[64 * 128];   // K ; later P(h2) at 0, P(h3) at 4096
    __shared__ _Float16 vth[128 * 64], vtl[128 * 64];  // V^T [d][tok]

    int tid = threadIdx.x;
    int w = tid >> 6, lane = tid & 63;
    int l15 = lane & 15, lg = lane >> 4;
    int wid = blockIdx.x;
    int wb = wid >> 8, wrr = (wid >> 4) & 15, wcc = wid & 15;
    const size_t base = ((size_t)wb * 16384 + (size_t)wrr * 1024 + (size_t)wcc * 8) * DIM;
    // token tt: float offset = base + (tt>>3)*16384 + (tt&7)*128

    // ---- LN1: 8 threads per token, 16 dims each ----
    {
        int tt = tid >> 3, sub = tid & 7;
        const float* xr = x + base + (size_t)(tt >> 3) * 16384 + (size_t)(tt & 7) * DIM + sub * 16;
        float v[16];
        float s = 0.f, sq = 0.f;
        #pragma unroll
        for (int j = 0; j < 4; ++j) {
            float4 t4 = *(const float4*)(xr + j * 4);
            v[4 * j] = t4.x; v[4 * j + 1] = t4.y; v[4 * j + 2] = t4.z; v[4 * j + 3] = t4.w;
            s += (t4.x + t4.y) + (t4.z + t4.w);
            sq = fmaf(t4.x, t4.x, fmaf(t4.y, t4.y, fmaf(t4.z, t4.z, fmaf(t4.w, t4.w, sq))));
        }
        s += __shfl_xor(s, 1); sq += __shfl_xor(sq, 1);
        s += __shfl_xor(s, 2); sq += __shfl_xor(sq, 2);
        s += __shfl_xor(s, 4); sq += __shfl_xor(sq, 4);
        float m = s * (1.f / DIM);
        float var = sq * (1.f / DIM) - m * m;
        float rs = rsqrtf(var + EPS);
        _Float16 hh[16], ll[16];
        #pragma unroll
        for (int j = 0; j < 16; ++j) {
            int k = sub * 16 + j;
            float a = (v[j] - m) * rs * ln_g[k] + ln_b[k];
            _Float16 h = (_Float16)a;
            hh[j] = h;
            ll[j] = (_Float16)((a - (float)h) * LO_SCALE);
        }
        *(f16x8*)&xoh[sw128(tt, sub * 16)]     = *(const f16x8*)&hh[0];
        *(f16x8*)&xoh[sw128(tt, sub * 16 + 8)] = *(const f16x8*)&hh[8];
        *(f16x8*)&xol[sw128(tt, sub * 16)]     = *(const f16x8*)&ll[0];
        *(f16x8*)&xol[sw128(tt, sub * 16 + 8)] = *(const f16x8*)&ll[8];
    }
    __syncthreads();   // (1)

    // ---- QKV GEMM: 384 cols / 8 waves = 3 col-tiles per wave ----
    #pragma unroll
    for (int ct = 0; ct < 3; ++ct) {
        int o = w * 48 + ct * 16 + l15;
        f16x8 bh[4], bl[4];
        #pragma unroll
        for (int ks = 0; ks < 4; ++ks) {
            size_t wo = (size_t)o * DIM + ks * 32 + lg * 8;
            bh[ks] = *(const f16x8*)(wq_h + wo);
            bl[ks] = *(const f16x8*)(wq_l + wo);
        }
        f32x4v am[4], ac[4];
        #pragma unroll
        for (int rt = 0; rt < 4; ++rt) { am[rt] = 0.0f; ac[rt] = 0.0f; }
        #pragma unroll
        for (int rt = 0; rt < 4; ++rt) {
            #pragma unroll
            for (int ks = 0; ks < 4; ++ks) {
                f16x8 ah = *(const f16x8*)&xoh[sw128(rt * 16 + l15, ks * 32 + lg * 8)];
                f16x8 al = *(const f16x8*)&xol[sw128(rt * 16 + l15, ks * 32 + lg * 8)];
                am[rt] = MFMA16(ah, bh[ks], am[rt]);
                ac[rt] = MFMA16(ah, bl[ks], ac[rt]);
                ac[rt] = MFMA16(al, bh[ks], ac[rt]);
            }
        }
        float bias = b_qkv[o];
        #pragma unroll
        for (int rt = 0; rt < 4; ++rt) {
            #pragma unroll
            for (int r = 0; r < 4; ++r) {
                int row = rt * 16 + lg * 4 + r;
                float val = am[rt][r] + ac[rt][r] * LO_INV + bias;
                _Float16 h = (_Float16)val;
                _Float16 lo = (_Float16)((val - (float)h) * LO_SCALE);
                if (o < 128)      { qh[sw128(row, o)] = h;        ql[sw128(row, o)] = lo; }
                else if (o < 256) { kh[sw128(row, o - 128)] = h;  kl[sw128(row, o - 128)] = lo; }
                else              { vth[sw64(o - 256, row)] = h;  vtl[sw64(o - 256, row)] = lo; }
            }
        }
    }
    __syncthreads();   // (2)

    // ---- scores + softmax, all heads in parallel: wave w -> head w&3, row-groups (w>>2)*2+t ----
    const float scale = 0.17677669529663687f;  // 1/sqrt(32)
    int h = w & 3;
    float preg[2][4][4];
    #pragma unroll
    for (int t = 0; t < 2; ++t) {
        int rg = (w >> 2) * 2 + t;
        f16x8 qah = *(const f16x8*)&qh[sw128(rg * 16 + l15, h * 32 + lg * 8)];
        f16x8 qal = *(const f16x8*)&ql[sw128(rg * 16 + l15, h * 32 + lg * 8)];
        f32x4v sm[4], sc2[4];
        #pragma unroll
        for (int ct = 0; ct < 4; ++ct) {
            f16x8 kbh = *(const f16x8*)&kh[sw128(ct * 16 + l15, h * 32 + lg * 8)];
            f16x8 kbl = *(const f16x8*)&kl[sw128(ct * 16 + l15, h * 32 + lg * 8)];
            sm[ct] = 0.0f; sc2[ct] = 0.0f;
            sm[ct] = MFMA16(qah, kbh, sm[ct]);
            sc2[ct] = MFMA16(qah, kbl, sc2[ct]);
            sc2[ct] = MFMA16(qal, kbh, sc2[ct]);
        }
        #pragma unroll
        for (int r = 0; r < 4; ++r) {
            float v0 = (sm[0][r] + sc2[0][r] * LO_INV) * scale;
            float v1 = (sm[1][r] + sc2[1][r] * LO_INV) * scale;
            float v2 = (sm[2][r] + sc2[2][r] * LO_INV) * scale;
            float v3 = (sm[3][r] + sc2[3][r] * LO_INV) * scale;
            float mx = fmaxf(fmaxf(v0, v1), fmaxf(v2, v3));
            mx = fmaxf(mx, __shfl_xor(mx, 1));
            mx = fmaxf(mx, __shfl_xor(mx, 2));
            mx = fmaxf(mx, __shfl_xor(mx, 4));
            mx = fmaxf(mx, __shfl_xor(mx, 8));
            float e0 = expf(v0 - mx), e1 = expf(v1 - mx), e2 = expf(v2 - mx), e3 = expf(v3 - mx);
            float ss = (e0 + e1) + (e2 + e3);
            ss += __shfl_xor(ss, 1); ss += __shfl_xor(ss, 2);
            ss += __shfl_xor(ss, 4); ss += __shfl_xor(ss, 8);
            float inv = 1.f / ss;
            preg[t][0][r] = e0 * inv;
            preg[t][1][r] = e1 * inv;
            preg[t][2][r] = e2 * inv;
            preg[t][3][r] = e3 * inv;
        }
    }
    __syncthreads();   // (3) all Q/K reads done -> safe to overlay P

    // ---- write P (hi/lo) into dead Q/K regions ----
    {
        _Float16* dsth = (h < 2) ? qh : kh;
        _Float16* dstl = (h < 2) ? ql : kl;
        int pb = (h & 1) * 4096;
        #pragma unroll
        for (int t = 0; t < 2; ++t) {
            int rg = (w >> 2) * 2 + t;
            #pragma unroll
            for (int ct = 0; ct < 4; ++ct) {
                #pragma unroll
                for (int r = 0; r < 4; ++r) {
                    float p = preg[t][ct][r];
                    int row = rg * 16 + lg * 4 + r, col = ct * 16 + l15;
                    _Float16 hh = (_Float16)p;
                    dsth[pb + sw64(row, col)] = hh;
                    dstl[pb + sw64(row, col)] = (_Float16)((p - (float)hh) * LO_SCALE);
                }
            }
        }
    }
    __syncthreads();   // (4)

    // ---- AV: O[rg*16..+16][h*32..+32] = P @ V ----
    {
        const _Float16* psh = (h < 2) ? qh : kh;
        const _Float16* psl = (h < 2) ? ql : kl;
        int pb = (h & 1) * 4096;
        #pragma unroll
        for (int t = 0; t < 2; ++t) {
            int rg = (w >> 2) * 2 + t;
            f32x4v om[2], oc[2];
            om[0] = 0.0f; om[1] = 0.0f; oc[0] = 0.0f; oc[1] = 0.0f;
            #pragma unroll
            for (int ks = 0; ks < 2; ++ks) {
                f16x8 pah = *(const f16x8*)&psh[pb + sw64(rg * 16 + l15, ks * 32 + lg * 8)];
                f16x8 pal = *(const f16x8*)&psl[pb + sw64(rg * 16 + l15, ks * 32 + lg * 8)];
                #pragma unroll
                for (int ct = 0; ct < 2; ++ct) {
                    f16x8 vbh = *(const f16x8*)&vth[sw64(h * 32 + ct * 16 + l15, ks * 32 + lg * 8)];
                    f16x8 vbl = *(const f16x8*)&vtl[sw64(h * 32 + ct * 16 + l15, ks * 32 + lg * 8)];
                    om[ct] = MFMA16(pah, vbh, om[ct]);
                    oc[ct] = MFMA16(pah, vbl, oc[ct]);
                    oc[ct] = MFMA16(pal, vbh, oc[ct]);
                }
            }
            #pragma unroll
            for (int ct = 0; ct < 2; ++ct) {
                #pragma unroll
                for (int r = 0; r < 4; ++r) {
                    float val = om[ct][r] + oc[ct][r] * LO_INV;
                    int row = rg * 16 + lg * 4 + r, col = h * 32 + ct * 16 + l15;
                    _Float16 hh = (_Float16)val;
                    xoh[sw128(row, col)] = hh;
                    xol[sw128(row, col)] = (_Float16)((val - (float)hh) * LO_SCALE);
                }
            }
        }
    }
    __syncthreads();   // (5)

    // ---- proj + residual: wave w -> rows (w&3)*16, cols (w>>2)*64 ----
    {
        int rt = w & 3, cb = (w >> 2) * 64;
        f32x4v pm[4], pc[4];
        #pragma unroll
        for (int ct = 0; ct < 4; ++ct) { pm[ct] = 0.0f; pc[ct] = 0.0f; }
        #pragma unroll
        for (int ks = 0; ks < 4; ++ks) {
            f16x8 ah = *(const f16x8*)&xoh[sw128(rt * 16 + l15, ks * 32 + lg * 8)];
            f16x8 al = *(const f16x8*)&xol[sw128(rt * 16 + l15, ks * 32 + lg * 8)];
            #pragma unroll
            for (int ct = 0; ct < 4; ++ct) {
                int c = cb + ct * 16 + l15;
                f16x8 bh = *(const f16x8*)(wp_h + (size_t)c * DIM + ks * 32 + lg * 8);
                f16x8 bl = *(const f16x8*)(wp_l + (size_t)c * DIM + ks * 32 + lg * 8);
                pm[ct] = MFMA16(ah, bh, pm[ct]);
                pc[ct] = MFMA16(ah, bl, pc[ct]);
                pc[ct] = MFMA16(al, bh, pc[ct]);
            }
        }
        #pragma unroll
        for (int ct = 0; ct < 4; ++ct) {
            int c = cb + ct * 16 + l15;
            float bp = b_proj[c];
            #pragma unroll
            for (int r = 0; r < 4; ++r) {
                int q = rt * 16 + lg * 4 + r;
                size_t go = base + (size_t)(q >> 3) * 16384 + (size_t)(q & 7) * DIM + c;
                x2[go] = x[go] + (pm[ct][r] + pc[ct][r] * LO_INV + bp);
            }
        }
    }
}

// ---------------- LN2 + gate + routing + scatter (block per 64 tokens) ----------------
__global__ __launch_bounds__(256) void k_ln2_gate(
    const float* __restrict__ x2, const float* __restrict__ g, const float* __restrict__ b,
    const float* __restrict__ gw, _Float16* __restrict__ y2,
    float* __restrict__ wgt, int* __restrict__ perm, int* __restrict__ counts)
{
    __shared__ float yt[64][129];    // fp32 LN output (conflict-free stride)
    __shared__ float lgs[64][17];    // gate logits
    int tid = threadIdx.x;
    size_t t0 = (size_t)blockIdx.x * 64;

    // ---- LN2: 4 threads per token ----
    {
        int tt = tid >> 2, sub = tid & 3;
        const float* xr = x2 + (t0 + tt) * DIM + sub * 32;
        float v[32];
        float s = 0.f, sq = 0.f;
        #pragma unroll
        for (int j = 0; j < 8; ++j) {
            float4 t4 = *(const float4*)(xr + j * 4);
            v[4 * j] = t4.x; v[4 * j + 1] = t4.y; v[4 * j + 2] = t4.z; v[4 * j + 3] = t4.w;
            s += (t4.x + t4.y) + (t4.z + t4.w);
            sq = fmaf(t4.x, t4.x, fmaf(t4.y, t4.y, fmaf(t4.z, t4.z, fmaf(t4.w, t4.w, sq))));
        }
        s += __shfl_xor(s, 1); sq += __shfl_xor(sq, 1);
        s += __shfl_xor(s, 2); sq += __shfl_xor(sq, 2);
        float m = s * (1.f / DIM);
        float var = sq * (1.f / DIM) - m * m;
        float rs = rsqrtf(var + EPS);
        _Float16 hh[32];
        #pragma unroll
        for (int j = 0; j < 32; ++j) {
            int k = sub * 32 + j;
            float a = (v[j] - m) * rs * g[k] + b[k];
            yt[tt][k] = a;
            hh[j] = (_Float16)a;
        }
        #pragma unroll
        for (int j = 0; j < 4; ++j)
            *(f16x8*)(y2 + (t0 + tt) * DIM + sub * 32 + j * 8) = *(const f16x8*)&hh[j * 8];
    }
    __syncthreads();

    // ---- gate logits: thread -> (token = tid&63, experts eg*4..eg*4+3), fp32 ----
    {
        int tt = tid & 63, eg = tid >> 6;
        const float* g0 = gw + (eg * 4 + 0) * DIM;
        const float* g1 = gw + (eg * 4 + 1) * DIM;
        const float* g2 = gw + (eg * 4 + 2) * DIM;
        const float* g3 = gw + (eg * 4 + 3) * DIM;
        float a0 = 0.f, a1 = 0.f, a2 = 0.f, a3 = 0.f;
        #pragma unroll 8
        for (int k = 0; k < DIM; ++k) {
            float yv = yt[tt][k];
            a0 = fmaf(yv, g0[k], a0);
            a1 = fmaf(yv, g1[k], a1);
            a2 = fmaf(yv, g2[k], a2);
            a3 = fmaf(yv, g3[k], a3);
        }
        lgs[tt][eg * 4 + 0] = a0;
        lgs[tt][eg * 4 + 1] = a1;
        lgs[tt][eg * 4 + 2] = a2;
        lgs[tt][eg * 4 + 3] = a3;
    }
    __syncthreads();

    // ---- routing + ballot rank + scatter (wave 0, lane = token) ----
    if (tid < 64) {
        float mx = -1e30f; int am = 0;
        #pragma unroll
        for (int e = 0; e < NEXP; ++e) {
            float v = lgs[tid][e];
            if (v > mx) { mx = v; am = e; }
        }
        float ss = 0.f;
        #pragma unroll
        for (int e = 0; e < NEXP; ++e) ss += expf(lgs[tid][e] - mx);
        float p = 1.f / ss;
        wgt[t0 + tid] = p / (p + 1e-8f);

        int myrank = 0, mycnt = 0;
        #pragma unroll
        for (int e = 0; e < NEXP; ++e) {
            unsigned long long mask = __ballot(am == e);
            if (am == e) myrank = (int)__popcll(mask & ((1ull << tid) - 1));
            if (tid == e) mycnt = (int)__popcll(mask);
        }
        int base = 0;
        if (tid < NEXP) base = atomicAdd(&counts[tid * CPAD], mycnt);
        base = __shfl(base, am);
        perm[(size_t)am * T_TOK + base + myrank] = (int)(t0 + tid);
    }
}

// ---------------- expert FFN (f16 MFMA) + weighted residual ----------------
__global__ __launch_bounds__(256, 3) void k_expert(
    const _Float16* __restrict__ y2, const float* __restrict__ x2,
    const _Float16* __restrict__ w1h, const float* __restrict__ b1,
    const _Float16* __restrict__ w2h, const float* __restrict__ b2,
    const int* __restrict__ perm, const int* __restrict__ counts,
    const float* __restrict__ wgt, float* __restrict__ out)
{
    __shared__ _Float16 yt[64][136];
    __shared__ _Float16 ht[64][264];
    __shared__ int rows[64];

    int e = blockIdx.x >> 9, tile = blockIdx.x & 511;
    int cnt = counts[e * CPAD];
    int row0 = tile << 6;
    if (row0 >= cnt) return;
    int nr = min(64, cnt - row0);
    int tid = threadIdx.x, wv = tid >> 6, lane = tid & 63;
    int l15 = lane & 15, lg = lane >> 4;

    if (tid < 64) rows[tid] = (tid < nr) ? perm[(size_t)e * T_TOK + row0 + tid] : 0;
    __syncthreads();
    f16x8 vz = (_Float16)0.0f;
    for (int i = tid; i < 1024; i += 256) {
        int tt = i >> 4, k = (i & 15) * 8;
        f16x8 val = vz;
        if (tt < nr) val = *(const f16x8*)(y2 + (size_t)rows[tt] * DIM + k);
        *(f16x8*)&yt[tt][k] = val;
    }
    __syncthreads();

    // GEMM1: h = GELU(yt @ w1e^T + b1)  [64,256], wave -> 64 hid cols
    for (int ct = 0; ct < 4; ++ct) {
        int hid = wv * 64 + ct * 16 + l15;
        f16x8 bf[4];
        #pragma unroll
        for (int ks = 0; ks < 4; ++ks)
            bf[ks] = *(const f16x8*)(w1h + ((size_t)e * EHID + hid) * DIM + ks * 32 + lg * 8);
        f32x4v acc[4];
        #pragma unroll
        for (int rt = 0; rt < 4; ++rt) acc[rt] = 0.0f;
        #pragma unroll
        for (int rt = 0; rt < 4; ++rt)
            #pragma unroll
            for (int ks = 0; ks < 4; ++ks)
                acc[rt] = MFMA16(*(const f16x8*)&yt[rt * 16 + l15][ks * 32 + lg * 8], bf[ks], acc[rt]);
        float bb = b1[e * EHID + hid];
        #pragma unroll
        for (int rt = 0; rt < 4; ++rt) {
            #pragma unroll
            for (int r = 0; r < 4; ++r) {
                float a = acc[rt][r] + bb;
                float gl = 0.5f * a * (1.f + erff(a * 0.70710678118654752f));
                ht[rt * 16 + lg * 4 + r][hid] = (_Float16)gl;
            }
        }
    }
    __syncthreads();

    // GEMM2: o = ht @ w2e^T  [64,128], wave -> 32 out cols
    {
        f32x4v acc[4][2];
        #pragma unroll
        for (int rt = 0; rt < 4; ++rt) { acc[rt][0] = 0.0f; acc[rt][1] = 0.0f; }
        for (int ks = 0; ks < 8; ++ks) {
            f16x8 bf[2];
            #pragma unroll
            for (int ct = 0; ct < 2; ++ct) {
                int c = wv * 32 + ct * 16 + l15;
                bf[ct] = *(const f16x8*)(w2h + ((size_t)e * DIM + c) * EHID + ks * 32 + lg * 8);
            }
            #pragma unroll
            for (int rt = 0; rt < 4; ++rt) {
                f16x8 af = *(const f16x8*)&ht[rt * 16 + l15][ks * 32 + lg * 8];
                #pragma unroll
                for (int ct = 0; ct < 2; ++ct)
                    acc[rt][ct] = MFMA16(af, bf[ct], acc[rt][ct]);
            }
        }
        #pragma unroll
        for (int rt = 0; rt < 4; ++rt) {
            #pragma unroll
            for (int ct = 0; ct < 2; ++ct) {
                int c = wv * 32 + ct * 16 + l15;
                float bb = b2[e * DIM + c];
                #pragma unroll
                for (int r = 0; r < 4; ++r) {
                    int tt = rt * 16 + lg * 4 + r;
                    if (tt < nr) {
                        int gtok = rows[tt];
                        size_t go = (size_t)gtok * DIM + c;
                        out[go] = x2[go] + wgt[gtok] * (acc[rt][ct][r] + bb);
                    }
                }
            }
        }
    }
}

// ---------------- launch ----------------
extern "C" void kernel_launch(void* const* d_in, const int* in_sizes, int n_in,
                              void* d_out, int out_size, void* d_ws, size_t ws_size,
                              hipStream_t stream) {
    const float* x      = (const float*)d_in[0];
    const float* ln1_g  = (const float*)d_in[1];
    const float* ln1_b  = (const float*)d_in[2];
    const float* w_qkv  = (const float*)d_in[3];
    const float* b_qkv  = (const float*)d_in[4];
    const float* w_proj = (const float*)d_in[5];
    const float* b_proj = (const float*)d_in[6];
    const float* ln2_g  = (const float*)d_in[7];
    const float* ln2_b  = (const float*)d_in[8];
    const float* gate_w = (const float*)d_in[9];
    const float* w1     = (const float*)d_in[10];
    const float* b1     = (const float*)d_in[11];
    const float* w2     = (const float*)d_in[12];
    const float* b2     = (const float*)d_in[13];
    float* out = (float*)d_out;

    // workspace layout (all offsets 16B-aligned)
    char* p = (char*)d_ws;
    float* x2 = (float*)p;                 p += (size_t)T_TOK * DIM * 4;       // 16 MB
    _Float16* y2 = (_Float16*)p;           p += (size_t)T_TOK * DIM * 2;       // 8 MB
    _Float16* wq_h = (_Float16*)p;         p += 3 * DIM * DIM * 2;
    _Float16* wq_l = (_Float16*)p;         p += 3 * DIM * DIM * 2;
    _Float16* wp_h = (_Float16*)p;         p += DIM * DIM * 2;
    _Float16* wp_l = (_Float16*)p;         p += DIM * DIM * 2;
    _Float16* w1h = (_Float16*)p;          p += NEXP * EHID * DIM * 2;
    _Float16* w2h = (_Float16*)p;          p += NEXP * EHID * DIM * 2;
    float* wgt = (float*)p;                p += T_TOK * 4;
    int* perm = (int*)p;                   p += (size_t)NEXP * T_TOK * 4;      // 2 MB
    int* counts = (int*)p;                 p += NEXP * CPAD * 4;

    k_cvt<<<2048, 256, 0, stream>>>(w_qkv, w_proj, w1, w2, wq_h, wq_l, wp_h, wp_l,
                                    w1h, w2h, counts);
    k_attn<<<NWIN, 512, 0, stream>>>(x, ln1_g, ln1_b, wq_h, wq_l, b_qkv,
                                     wp_h, wp_l, b_proj, x2);
    k_ln2_gate<<<T_TOK / 64, 256, 0, stream>>>(x2, ln2_g, ln2_b, gate_w, y2, wgt, perm, counts);
    k_expert<<<NEXP * 512, 256, 0, stream>>>(y2, x2, w1h, b1, w2h, b2, perm, counts, wgt, out);
}